// Round 2
// baseline (349.314 us; speedup 1.0000x reference)
//
#include <hip/hip_runtime.h>
#include <hip/hip_bf16.h>

// Problem constants
constexpr int BB  = 4;     // batch
constexpr int CC  = 256;   // channels
constexpr int CQ  = 64;    // q/k channels
constexpr int NN  = 4096;  // H*W

typedef __attribute__((ext_vector_type(8))) short bf16x8;  // 8 bf16 (4 VGPRs)
typedef __attribute__((ext_vector_type(4))) float f32x4;   // MFMA accumulator

__device__ __forceinline__ short f2bf(float f) {
    unsigned u = __float_as_uint(f);
    unsigned r = u + 0x7fffu + ((u >> 16) & 1u);   // round-to-nearest-even
    return (short)(r >> 16);
}

// ---------------------------------------------------------------------------
// Kernel 1: QKV projection (unchanged from round 1).
// ---------------------------------------------------------------------------
__global__ void proj_kernel(const float* __restrict__ x,
                            const float* __restrict__ Wq, const float* __restrict__ bq,
                            const float* __restrict__ Wk, const float* __restrict__ bk,
                            const float* __restrict__ Wv, const float* __restrict__ bv,
                            short* __restrict__ Qt, short* __restrict__ Kt,
                            short* __restrict__ Vm) {
    const int b  = blockIdx.z;
    const int o0 = blockIdx.y * 8;                 // first of 8 output channels
    const int n0 = blockIdx.x * 512 + threadIdx.x; // first n
    const int n1 = n0 + 256;

    const float* W; const float* bias;
    if (o0 < 64)       { W = Wq + o0 * CC;         bias = bq + o0; }
    else if (o0 < 128) { W = Wk + (o0 - 64) * CC;  bias = bk + (o0 - 64); }
    else               { W = Wv + (o0 - 128) * CC; bias = bv + (o0 - 128); }

    const float* xb = x + (size_t)b * CC * NN;

    float acc0[8], acc1[8];
#pragma unroll
    for (int i = 0; i < 8; ++i) { acc0[i] = bias[i]; acc1[i] = bias[i]; }

#pragma unroll 4
    for (int c = 0; c < CC; ++c) {
        float x0 = xb[(size_t)c * NN + n0];
        float x1 = xb[(size_t)c * NN + n1];
#pragma unroll
        for (int oo = 0; oo < 8; ++oo) {
            float w = W[oo * CC + c];              // uniform -> scalar load
            acc0[oo] += w * x0;
            acc1[oo] += w * x1;
        }
    }

    if (o0 < 128) {
        short* base = (o0 < 64) ? (Qt + ((size_t)b * NN) * 64 + o0)
                                : (Kt + ((size_t)b * NN) * 64 + (o0 - 64));
        bf16x8 p0, p1;
#pragma unroll
        for (int oo = 0; oo < 8; ++oo) { p0[oo] = f2bf(acc0[oo]); p1[oo] = f2bf(acc1[oo]); }
        *(bf16x8*)(base + (size_t)n0 * 64) = p0;
        *(bf16x8*)(base + (size_t)n1 * 64) = p1;
    } else {
        short* vb = Vm + (size_t)b * CC * NN;
        int c0 = o0 - 128;
#pragma unroll
        for (int oo = 0; oo < 8; ++oo) {
            vb[(size_t)(c0 + oo) * NN + n0] = f2bf(acc0[oo]);
            vb[(size_t)(c0 + oo) * NN + n1] = f2bf(acc1[oo]);
        }
    }
}

// ---------------------------------------------------------------------------
// Kernel 2: flash attention.
//  PARTIAL=true : split-K. grid = 1024 x 1 (1D, XCD-swizzled: batch b owns
//    XCDs {2b,2b+1} so K/V (2.5MB/batch) stays L2-resident). Each block does
//    keys [ks*NN/KS, (ks+1)*NN/KS) for one 64-row q-tile and writes
//    unnormalized partials Opart[b][qt][ks][64][256] (+ m,l).
//  PARTIAL=false: round-1 direct path (fallback when ws too small).
// 4 waves/block, wave = 16 q-rows, fully wave-local online softmax.
// ---------------------------------------------------------------------------
template<int KS, bool PARTIAL>
__global__ __launch_bounds__(256, PARTIAL ? 4 : 2) void flash_kernel(
        const short* __restrict__ Qt, const short* __restrict__ Kt,
        const short* __restrict__ Vm,
        const float* __restrict__ x, const float* __restrict__ weightp,
        float* __restrict__ out,
        float* __restrict__ Opart, float* __restrict__ Mp, float* __restrict__ Lp) {
    int b, qt, ks;
    if (PARTIAL) {
        // KS==4, grid 1024: id -> (xcd, sub); batch = xcd>>1.
        const int id  = blockIdx.x;
        const int xcd = id & 7, sub = id >> 3;
        b = xcd >> 1;
        const int flat = sub + ((xcd & 1) << 7);   // 0..255
        qt = flat & 63;
        ks = flat >> 6;                            // 0..KS-1
    } else {
        b = blockIdx.x; qt = blockIdx.y; ks = 0;
    }
    const int wave = threadIdx.x >> 6;
    const int lane = threadIdx.x & 63;
    const int l15  = lane & 15;
    const int g    = lane >> 4;

    const int qbase = qt * 64 + wave * 16;

    const short* Qb = Qt + (size_t)b * NN * 64;
    const short* Kb = Kt + (size_t)b * NN * 64;
    const short* Vb = Vm + (size_t)b * CC * NN;

    bf16x8 qf0 = *(const bf16x8*)(Qb + (size_t)(qbase + l15) * 64 + 0  + g * 8);
    bf16x8 qf1 = *(const bf16x8*)(Qb + (size_t)(qbase + l15) * 64 + 32 + g * 8);

    float m[4], lsum[4];
#pragma unroll
    for (int r = 0; r < 4; ++r) { m[r] = -1e30f; lsum[r] = 0.0f; }
    f32x4 oacc[16];
#pragma unroll
    for (int ch = 0; ch < 16; ++ch) oacc[ch] = (f32x4){0.f, 0.f, 0.f, 0.f};

    __shared__ short plds[4][16][72];              // +8 pad: 2-way banks only
    short (*pl)[72] = plds[wave];

    const int kt0 = ks * (NN / KS) / 64;
    const int nkt = (NN / KS) / 64;
    for (int kt = kt0; kt < kt0 + nkt; ++kt) {
        const int kbase = kt * 64;

        // ---- S = Q K^T  (16 x 64 per wave) ----
        f32x4 s[4];
#pragma unroll
        for (int jt = 0; jt < 4; ++jt) {
            const short* kr = Kb + (size_t)(kbase + jt * 16 + l15) * 64 + g * 8;
            bf16x8 kf0 = *(const bf16x8*)(kr);
            bf16x8 kf1 = *(const bf16x8*)(kr + 32);
            f32x4 a = (f32x4){0.f, 0.f, 0.f, 0.f};
            a = __builtin_amdgcn_mfma_f32_16x16x32_bf16(qf0, kf0, a, 0, 0, 0);
            a = __builtin_amdgcn_mfma_f32_16x16x32_bf16(qf1, kf1, a, 0, 0, 0);
            s[jt] = a;
        }

        // ---- row max (16-lane butterfly) ----
        float scale[4];
#pragma unroll
        for (int r = 0; r < 4; ++r) {
            float v = fmaxf(fmaxf(s[0][r], s[1][r]), fmaxf(s[2][r], s[3][r]));
            v = fmaxf(v, __shfl_xor(v, 1));
            v = fmaxf(v, __shfl_xor(v, 2));
            v = fmaxf(v, __shfl_xor(v, 4));
            v = fmaxf(v, __shfl_xor(v, 8));
            float mn = fmaxf(m[r], v);
            scale[r] = __expf(m[r] - mn);
            m[r] = mn;
        }

        // ---- P = exp(S-m), row sums ----
#pragma unroll
        for (int jt = 0; jt < 4; ++jt)
#pragma unroll
            for (int r = 0; r < 4; ++r)
                s[jt][r] = __expf(s[jt][r] - m[r]);

#pragma unroll
        for (int r = 0; r < 4; ++r) {
            float v = s[0][r] + s[1][r] + s[2][r] + s[3][r];
            v += __shfl_xor(v, 1);
            v += __shfl_xor(v, 2);
            v += __shfl_xor(v, 4);
            v += __shfl_xor(v, 8);
            lsum[r] = lsum[r] * scale[r] + v;
        }

#pragma unroll
        for (int ch = 0; ch < 16; ++ch) {
#pragma unroll
            for (int r = 0; r < 4; ++r) oacc[ch][r] *= scale[r];
        }

        // ---- P -> LDS -> A-fragment layout ----
#pragma unroll
        for (int jt = 0; jt < 4; ++jt)
#pragma unroll
            for (int r = 0; r < 4; ++r)
                pl[g * 4 + r][jt * 16 + l15] = f2bf(s[jt][r]);

        bf16x8 pf0 = *(const bf16x8*)&pl[l15][0  + g * 8];
        bf16x8 pf1 = *(const bf16x8*)&pl[l15][32 + g * 8];

        // ---- O += P V ----
#pragma unroll
        for (int ch = 0; ch < 16; ++ch) {
            const short* vr = Vb + (size_t)(ch * 16 + l15) * NN + kbase + g * 8;
            bf16x8 vf0 = *(const bf16x8*)(vr);
            bf16x8 vf1 = *(const bf16x8*)(vr + 32);
            oacc[ch] = __builtin_amdgcn_mfma_f32_16x16x32_bf16(pf0, vf0, oacc[ch], 0, 0, 0);
            oacc[ch] = __builtin_amdgcn_mfma_f32_16x16x32_bf16(pf1, vf1, oacc[ch], 0, 0, 0);
        }
    }

    if (PARTIAL) {
        // Opart[b][qt][ks][row64][ch]; Mp/Lp[b][qt][ks][row64]
        const size_t pbase = (((size_t)(b * 64 + qt) * KS + ks) * 64) * 256;
#pragma unroll
        for (int ch = 0; ch < 16; ++ch)
#pragma unroll
            for (int r = 0; r < 4; ++r)
                Opart[pbase + (size_t)(wave * 16 + g * 4 + r) * 256 + ch * 16 + l15] =
                    oacc[ch][r];
        if (l15 == 0) {
            const size_t mb = ((size_t)(b * 64 + qt) * KS + ks) * 64 + wave * 16;
#pragma unroll
            for (int r = 0; r < 4; ++r) {
                Mp[mb + g * 4 + r] = m[r];
                Lp[mb + g * 4 + r] = lsum[r];
            }
        }
    } else {
        const float wgt = weightp[0];
        float rinv[4];
#pragma unroll
        for (int r = 0; r < 4; ++r) rinv[r] = wgt / lsum[r];
        const int qrow0 = qbase + g * 4;
        const float* xb = x + (size_t)b * CC * NN;
        float* ob = out + (size_t)b * CC * NN;
#pragma unroll
        for (int ch = 0; ch < 16; ++ch) {
            int c = ch * 16 + l15;
            size_t base = (size_t)c * NN + qrow0;
            float4 xv = *(const float4*)(xb + base);
            float4 ov;
            ov.x = oacc[ch][0] * rinv[0] + xv.x;
            ov.y = oacc[ch][1] * rinv[1] + xv.y;
            ov.z = oacc[ch][2] * rinv[2] + xv.z;
            ov.w = oacc[ch][3] * rinv[3] + xv.w;
            *(float4*)(ob + base) = ov;
        }
    }
}

// ---------------------------------------------------------------------------
// Kernel 3: split-K combine + residual epilogue.
// grid (B, N/32), block 256. Each block: 32 q-rows x 256 channels.
// Stage 0: per-row softmax merge factors. Stage 1: coalesced partial reads ->
// combined O in LDS [32][257]. Stage 2: transposed write out[b][c][n] + x.
// ---------------------------------------------------------------------------
template<int KS>
__global__ __launch_bounds__(256) void combine_kernel(
        const float* __restrict__ Opart, const float* __restrict__ Mp,
        const float* __restrict__ Lp, const float* __restrict__ x,
        const float* __restrict__ weightp, float* __restrict__ out) {
    const int b     = blockIdx.x;
    const int rowg0 = blockIdx.y * 32;             // first global q-row
    const int qt    = rowg0 >> 6;                  // 64-row partial tile
    const int rbase = rowg0 & 63;                  // 0 or 32 within tile
    const int t     = threadIdx.x;

    __shared__ float oc[32][257];
    __shared__ float coeff[32][KS];
    __shared__ float linv[32];

    if (t < 32) {
        const size_t mb = ((size_t)(b * 64 + qt) * KS) * 64 + rbase + t;
        float mm[KS], ll[KS], M = -1e30f;
#pragma unroll
        for (int s = 0; s < KS; ++s) {
            mm[s] = Mp[mb + (size_t)s * 64];
            ll[s] = Lp[mb + (size_t)s * 64];
            M = fmaxf(M, mm[s]);
        }
        float L = 0.f;
#pragma unroll
        for (int s = 0; s < KS; ++s) {
            float c = __expf(mm[s] - M);
            coeff[t][s] = c;
            L += c * ll[s];
        }
        linv[t] = 1.0f / L;
    }
    __syncthreads();

    const size_t ob = (((size_t)(b * 64 + qt) * KS) * 64 + rbase) * 256;
#pragma unroll 4
    for (int row = 0; row < 32; ++row) {
        float acc = 0.f;
#pragma unroll
        for (int s = 0; s < KS; ++s)
            acc += coeff[row][s] * Opart[ob + (size_t)s * 64 * 256 + row * 256 + t];
        oc[row][t] = acc * linv[row];
    }
    __syncthreads();

    const float wgt = weightp[0];
    const int row = t & 31, cg = t >> 5;           // 8 channel groups
    const float* xb = x + (size_t)b * CC * NN + rowg0 + row;
    float* op = out + (size_t)b * CC * NN + rowg0 + row;
#pragma unroll 4
    for (int c = cg; c < 256; c += 8) {
        op[(size_t)c * NN] = wgt * oc[row][c] + xb[(size_t)c * NN];
    }
}

extern "C" void kernel_launch(void* const* d_in, const int* in_sizes, int n_in,
                              void* d_out, int out_size, void* d_ws, size_t ws_size,
                              hipStream_t stream) {
    const float* feat = (const float*)d_in[0];
    const float* Wq   = (const float*)d_in[1];
    const float* bq   = (const float*)d_in[2];
    const float* Wk   = (const float*)d_in[3];
    const float* bk   = (const float*)d_in[4];
    const float* Wv   = (const float*)d_in[5];
    const float* bv   = (const float*)d_in[6];
    const float* wgt  = (const float*)d_in[7];
    float* out = (float*)d_out;

    constexpr int KS = 4;
    short* Qt = (short*)d_ws;                       // [B][N][64]
    short* Kt = Qt + (size_t)BB * NN * CQ;          // [B][N][64]
    short* Vm = Kt + (size_t)BB * NN * CQ;          // [B][256][N]
    float* Opart = (float*)(Vm + (size_t)BB * CC * NN);   // [B][64][KS][64][256]
    float* Mp = Opart + (size_t)BB * 64 * KS * 64 * 256;  // [B][64][KS][64]
    float* Lp = Mp + (size_t)BB * 64 * KS * 64;

    const size_t need = (size_t)BB * NN * CQ * 2 * sizeof(short)
                      + (size_t)BB * CC * NN * sizeof(short)
                      + (size_t)BB * 64 * KS * 64 * 256 * sizeof(float)
                      + (size_t)BB * 64 * KS * 64 * 2 * sizeof(float);

    proj_kernel<<<dim3(NN / 512, 48, BB), 256, 0, stream>>>(
        feat, Wq, bq, Wk, bk, Wv, bv, Qt, Kt, Vm);

    if (ws_size >= need) {
        flash_kernel<KS, true><<<dim3(BB * 64 * KS), 256, 0, stream>>>(
            Qt, Kt, Vm, feat, wgt, out, Opart, Mp, Lp);
        combine_kernel<KS><<<dim3(BB, NN / 32), 256, 0, stream>>>(
            Opart, Mp, Lp, feat, wgt, out);
    } else {
        flash_kernel<1, false><<<dim3(BB, NN / 64), 256, 0, stream>>>(
            Qt, Kt, Vm, feat, wgt, out, nullptr, nullptr, nullptr);
    }
}

// Round 3
// 149.055 us; speedup vs baseline: 2.3435x; 2.3435x over previous
//
#include <hip/hip_runtime.h>
#include <hip/hip_bf16.h>

// Problem constants
constexpr int BB  = 4;     // batch
constexpr int CC  = 256;   // channels
constexpr int CQ  = 64;    // q/k channels
constexpr int NN  = 4096;  // H*W
constexpr int KS  = 4;     // key-split factor
constexpr int QTR = 128;   // q-rows per block (4 waves x 32 rows)

typedef __attribute__((ext_vector_type(8))) short bf16x8;  // 8 bf16 (4 VGPRs)
typedef __attribute__((ext_vector_type(4))) float f32x4;   // MFMA accumulator

__device__ __forceinline__ short f2bf(float f) {
    unsigned u = __float_as_uint(f);
    unsigned r = u + 0x7fffu + ((u >> 16) & 1u);   // round-to-nearest-even
    return (short)(r >> 16);
}

// async global->LDS, 16B per lane; LDS dest = wave-uniform base + lane*16
__device__ __forceinline__ void gload16(const void* gsrc, void* ldst) {
    __builtin_amdgcn_global_load_lds(
        (const __attribute__((address_space(1))) unsigned int*)gsrc,
        (__attribute__((address_space(3))) unsigned int*)ldst, 16, 0, 0);
}

// ---------------------------------------------------------------------------
// Kernel 1: QKV projection (unchanged; ~30us, revisit later if it matters).
// ---------------------------------------------------------------------------
__global__ void proj_kernel(const float* __restrict__ x,
                            const float* __restrict__ Wq, const float* __restrict__ bq,
                            const float* __restrict__ Wk, const float* __restrict__ bk,
                            const float* __restrict__ Wv, const float* __restrict__ bv,
                            short* __restrict__ Qt, short* __restrict__ Kt,
                            short* __restrict__ Vm) {
    const int b  = blockIdx.z;
    const int o0 = blockIdx.y * 8;
    const int n0 = blockIdx.x * 512 + threadIdx.x;
    const int n1 = n0 + 256;

    const float* W; const float* bias;
    if (o0 < 64)       { W = Wq + o0 * CC;         bias = bq + o0; }
    else if (o0 < 128) { W = Wk + (o0 - 64) * CC;  bias = bk + (o0 - 64); }
    else               { W = Wv + (o0 - 128) * CC; bias = bv + (o0 - 128); }

    const float* xb = x + (size_t)b * CC * NN;

    float acc0[8], acc1[8];
#pragma unroll
    for (int i = 0; i < 8; ++i) { acc0[i] = bias[i]; acc1[i] = bias[i]; }

#pragma unroll 4
    for (int c = 0; c < CC; ++c) {
        float x0 = xb[(size_t)c * NN + n0];
        float x1 = xb[(size_t)c * NN + n1];
#pragma unroll
        for (int oo = 0; oo < 8; ++oo) {
            float w = W[oo * CC + c];
            acc0[oo] += w * x0;
            acc1[oo] += w * x1;
        }
    }

    if (o0 < 128) {
        short* base = (o0 < 64) ? (Qt + ((size_t)b * NN) * 64 + o0)
                                : (Kt + ((size_t)b * NN) * 64 + (o0 - 64));
        bf16x8 p0, p1;
#pragma unroll
        for (int oo = 0; oo < 8; ++oo) { p0[oo] = f2bf(acc0[oo]); p1[oo] = f2bf(acc1[oo]); }
        *(bf16x8*)(base + (size_t)n0 * 64) = p0;
        *(bf16x8*)(base + (size_t)n1 * 64) = p1;
    } else {
        short* vb = Vm + (size_t)b * CC * NN;
        int c0 = o0 - 128;
#pragma unroll
        for (int oo = 0; oo < 8; ++oo) {
            vb[(size_t)(c0 + oo) * NN + n0] = f2bf(acc0[oo]);
            vb[(size_t)(c0 + oo) * NN + n1] = f2bf(acc1[oo]);
        }
    }
}

// ---------------------------------------------------------------------------
// Kernel 2: flash attention, LDS-staged K/V.
// grid = 512 blocks (1D, XCD-swizzled: batch b pinned to XCDs {2b,2b+1} so
// K/V (2.5MB/batch) is L2-resident). Block = 4 waves x 32 q-rows = 128-row
// Q-tile; iterates 16 key-tiles of 64 (its KS slice); writes unnormalized
// partials Opart[pt][128][256] (+ m,l).
//
// K/V tiles staged in LDS by global_load_lds w/ XOR swizzle:
//   LDS(row, colL) = G(row, colL ^ ((row&7)<<4))   [16B granules, 128B rows]
// achieved by pre-swizzling the per-lane GLOBAL source (LDS dest is linear).
// Fragment ds_read_b128 applies the same XOR -> ~2-way conflicts (free).
// ---------------------------------------------------------------------------
__global__ __launch_bounds__(256, 2) void flash_kernel(
        const short* __restrict__ Qt, const short* __restrict__ Kt,
        const short* __restrict__ Vm,
        float* __restrict__ Opart, float* __restrict__ Mp, float* __restrict__ Lp) {
    const int id  = blockIdx.x;
    const int xcd = id & 7, sub = id >> 3;       // 8 XCDs round-robin
    const int b   = xcd >> 1;                    // batch -> XCD pair
    const int qt  = sub & 31;                    // 32 q-tiles per batch
    const int ks  = ((xcd & 1) << 1) | (sub >> 5);  // 0..3 key-split

    const int wave = threadIdx.x >> 6;
    const int lane = threadIdx.x & 63;
    const int l15  = lane & 15;
    const int g    = lane >> 4;

    __shared__ short Kl[64 * 64];      // [key][64 k-dims]  swizzled, 8KB
    __shared__ short Vl[256 * 64];     // [ch][64 keys]     swizzled, 32KB
    __shared__ short pl[4][32][72];    // per-wave P transpose buf (+8 pad)

    const short* Qb = Qt + (size_t)b * NN * 64;
    const short* Kb = Kt + (size_t)b * NN * 64;
    const short* Vb = Vm + (size_t)b * CC * NN;

    const int qbase = qt * QTR + wave * 32;

    // Q fragments: 2 row-frags x 2 k-chunks, persistent in regs (16 VGPR)
    bf16x8 qf[2][2];
#pragma unroll
    for (int rf = 0; rf < 2; ++rf)
#pragma unroll
        for (int kk = 0; kk < 2; ++kk)
            qf[rf][kk] = *(const bf16x8*)(Qb + (size_t)(qbase + rf * 16 + l15) * 64
                                          + kk * 32 + g * 8);

    float m[2][4], lsum[2][4];
#pragma unroll
    for (int rf = 0; rf < 2; ++rf)
#pragma unroll
        for (int r = 0; r < 4; ++r) { m[rf][r] = -1e30f; lsum[rf][r] = 0.0f; }

    f32x4 oacc[2][16];                  // 128 accumulator regs (AGPR)
#pragma unroll
    for (int rf = 0; rf < 2; ++rf)
#pragma unroll
        for (int ch = 0; ch < 16; ++ch) oacc[rf][ch] = (f32x4){0.f, 0.f, 0.f, 0.f};

    // staging constants: seg = 1KB = 8 rows of 128B; lane covers row s*8+(lane>>3),
    // 16B granule (lane&7); pre-swizzled source column:
    const int row_off = lane >> 3;                          // row&7 within seg
    const int scol    = (((lane & 7) ^ row_off) << 4);      // source col byte

    const int kt0 = ks * (NN / KS / 64);
    for (int it = 0; it < NN / KS / 64; ++it) {
        const int kbase = (kt0 + it) * 64;

        __syncthreads();   // previous tile fully consumed before overwrite
        // 40 x 1KB segments: 0..31 V, 32..39 K; wave w takes segs w, w+4, ...
#pragma unroll
        for (int s = wave; s < 40; s += 4) {
            if (s < 32) {
                const char* src = (const char*)(Vb + (size_t)(s * 8 + row_off) * NN
                                                + kbase) + scol;
                gload16(src, (char*)Vl + s * 1024);
            } else {
                const char* src = (const char*)(Kb + (size_t)(kbase + (s - 32) * 8
                                                + row_off) * 64) + scol;
                gload16(src, (char*)Kl + (s - 32) * 1024);
            }
        }
        __syncthreads();   // compiler drains vmcnt(0) before s_barrier

        // ---- S = Q K^T : 32 rows x 64 keys per wave ----
        f32x4 s2[2][4];
#pragma unroll
        for (int jt = 0; jt < 4; ++jt) {
            const int krow = jt * 16 + l15;
            const int sw   = (krow & 7) << 4;
            const char* kr = (const char*)Kl + krow * 128;
            bf16x8 kf0 = *(const bf16x8*)(kr + ((g * 16) ^ sw));
            bf16x8 kf1 = *(const bf16x8*)(kr + ((64 + g * 16) ^ sw));
#pragma unroll
            for (int rf = 0; rf < 2; ++rf) {
                f32x4 a = (f32x4){0.f, 0.f, 0.f, 0.f};
                a = __builtin_amdgcn_mfma_f32_16x16x32_bf16(qf[rf][0], kf0, a, 0, 0, 0);
                a = __builtin_amdgcn_mfma_f32_16x16x32_bf16(qf[rf][1], kf1, a, 0, 0, 0);
                s2[rf][jt] = a;
            }
        }

        // ---- online softmax per row-frag ----
        float scale[2][4];
#pragma unroll
        for (int rf = 0; rf < 2; ++rf) {
#pragma unroll
            for (int r = 0; r < 4; ++r) {
                float v = fmaxf(fmaxf(s2[rf][0][r], s2[rf][1][r]),
                                fmaxf(s2[rf][2][r], s2[rf][3][r]));
                v = fmaxf(v, __shfl_xor(v, 1));
                v = fmaxf(v, __shfl_xor(v, 2));
                v = fmaxf(v, __shfl_xor(v, 4));
                v = fmaxf(v, __shfl_xor(v, 8));
                float mn = fmaxf(m[rf][r], v);
                scale[rf][r] = __expf(m[rf][r] - mn);
                m[rf][r] = mn;
            }
#pragma unroll
            for (int jt = 0; jt < 4; ++jt)
#pragma unroll
                for (int r = 0; r < 4; ++r)
                    s2[rf][jt][r] = __expf(s2[rf][jt][r] - m[rf][r]);
#pragma unroll
            for (int r = 0; r < 4; ++r) {
                float v = s2[rf][0][r] + s2[rf][1][r] + s2[rf][2][r] + s2[rf][3][r];
                v += __shfl_xor(v, 1);
                v += __shfl_xor(v, 2);
                v += __shfl_xor(v, 4);
                v += __shfl_xor(v, 8);
                lsum[rf][r] = lsum[rf][r] * scale[rf][r] + v;
            }
            // P -> per-wave LDS (transpose to A-fragment layout)
#pragma unroll
            for (int jt = 0; jt < 4; ++jt)
#pragma unroll
                for (int r = 0; r < 4; ++r)
                    pl[wave][rf * 16 + g * 4 + r][jt * 16 + l15] = f2bf(s2[rf][jt][r]);
        }

        // ---- rescale O ----
#pragma unroll
        for (int rf = 0; rf < 2; ++rf)
#pragma unroll
            for (int ch = 0; ch < 16; ++ch)
#pragma unroll
                for (int r = 0; r < 4; ++r) oacc[rf][ch][r] *= scale[rf][r];

        bf16x8 pf[2][2];
#pragma unroll
        for (int rf = 0; rf < 2; ++rf)
#pragma unroll
            for (int kk = 0; kk < 2; ++kk)
                pf[rf][kk] = *(const bf16x8*)&pl[wave][rf * 16 + l15][kk * 32 + g * 8];

        // ---- O += P V : 32 rows x 256 ch per wave ----
#pragma unroll
        for (int ch = 0; ch < 16; ++ch) {
            const int vrow = ch * 16 + l15;
            const int sw   = (vrow & 7) << 4;
            const char* vr = (const char*)Vl + vrow * 128;
            bf16x8 vf0 = *(const bf16x8*)(vr + ((g * 16) ^ sw));
            bf16x8 vf1 = *(const bf16x8*)(vr + ((64 + g * 16) ^ sw));
#pragma unroll
            for (int rf = 0; rf < 2; ++rf) {
                oacc[rf][ch] = __builtin_amdgcn_mfma_f32_16x16x32_bf16(pf[rf][0], vf0,
                                                                       oacc[rf][ch], 0, 0, 0);
                oacc[rf][ch] = __builtin_amdgcn_mfma_f32_16x16x32_bf16(pf[rf][1], vf1,
                                                                       oacc[rf][ch], 0, 0, 0);
            }
        }
    }

    // ---- epilogue: unnormalized partials ----
    const int pt = (b * 32 + qt) * KS + ks;
    float* Op = Opart + (size_t)pt * QTR * 256;
#pragma unroll
    for (int rf = 0; rf < 2; ++rf)
#pragma unroll
        for (int ch = 0; ch < 16; ++ch)
#pragma unroll
            for (int r = 0; r < 4; ++r)
                Op[(size_t)(wave * 32 + rf * 16 + g * 4 + r) * 256 + ch * 16 + l15] =
                    oacc[rf][ch][r];
    if (l15 == 0) {
        const size_t mb = (size_t)pt * QTR + wave * 32;
#pragma unroll
        for (int rf = 0; rf < 2; ++rf)
#pragma unroll
            for (int r = 0; r < 4; ++r) {
                Mp[mb + rf * 16 + g * 4 + r] = m[rf][r];
                Lp[mb + rf * 16 + g * 4 + r] = lsum[rf][r];
            }
    }
}

// ---------------------------------------------------------------------------
// Kernel 3: split-K combine + residual epilogue.
// grid (B, N/32), block 256. 32 q-rows x 256 channels per block.
// ---------------------------------------------------------------------------
__global__ __launch_bounds__(256) void combine_kernel(
        const float* __restrict__ Opart, const float* __restrict__ Mp,
        const float* __restrict__ Lp, const float* __restrict__ x,
        const float* __restrict__ weightp, float* __restrict__ out) {
    const int b     = blockIdx.x;
    const int rowg0 = blockIdx.y * 32;             // first global q-row
    const int qt    = rowg0 >> 7;                  // 128-row partial tile
    const int rbase = rowg0 & 127;                 // offset within tile
    const int t     = threadIdx.x;

    __shared__ float oc[32][257];
    __shared__ float coeff[32][KS];
    __shared__ float linv[32];

    const int pt0 = (b * 32 + qt) * KS;

    if (t < 32) {
        const size_t mb = (size_t)pt0 * QTR + rbase + t;
        float mm[KS], ll[KS], M = -1e30f;
#pragma unroll
        for (int s = 0; s < KS; ++s) {
            mm[s] = Mp[mb + (size_t)s * QTR];
            ll[s] = Lp[mb + (size_t)s * QTR];
            M = fmaxf(M, mm[s]);
        }
        float L = 0.f;
#pragma unroll
        for (int s = 0; s < KS; ++s) {
            float c = __expf(mm[s] - M);
            coeff[t][s] = c;
            L += c * ll[s];
        }
        linv[t] = 1.0f / L;
    }
    __syncthreads();

    const size_t ob = (size_t)pt0 * QTR * 256 + (size_t)rbase * 256;
#pragma unroll 4
    for (int row = 0; row < 32; ++row) {
        float acc = 0.f;
#pragma unroll
        for (int s = 0; s < KS; ++s)
            acc += coeff[row][s] * Opart[ob + (size_t)s * QTR * 256 + row * 256 + t];
        oc[row][t] = acc * linv[row];
    }
    __syncthreads();

    const float wgt = weightp[0];
    const int row = t & 31, cg = t >> 5;           // 8 channel groups
    const float* xb = x + (size_t)b * CC * NN + rowg0 + row;
    float* op = out + (size_t)b * CC * NN + rowg0 + row;
#pragma unroll 4
    for (int c = cg; c < 256; c += 8) {
        op[(size_t)c * NN] = wgt * oc[row][c] + xb[(size_t)c * NN];
    }
}

extern "C" void kernel_launch(void* const* d_in, const int* in_sizes, int n_in,
                              void* d_out, int out_size, void* d_ws, size_t ws_size,
                              hipStream_t stream) {
    const float* feat = (const float*)d_in[0];
    const float* Wq   = (const float*)d_in[1];
    const float* bq   = (const float*)d_in[2];
    const float* Wk   = (const float*)d_in[3];
    const float* bk   = (const float*)d_in[4];
    const float* Wv   = (const float*)d_in[5];
    const float* bv   = (const float*)d_in[6];
    const float* wgt  = (const float*)d_in[7];
    float* out = (float*)d_out;

    short* Qt = (short*)d_ws;                       // [B][N][64]
    short* Kt = Qt + (size_t)BB * NN * CQ;          // [B][N][64]
    short* Vm = Kt + (size_t)BB * NN * CQ;          // [B][256][N]
    float* Opart = (float*)(Vm + (size_t)BB * CC * NN);    // [512][128][256]
    float* Mp = Opart + (size_t)BB * 32 * KS * QTR * 256;  // [512][128]
    float* Lp = Mp + (size_t)BB * 32 * KS * QTR;

    proj_kernel<<<dim3(NN / 512, 48, BB), 256, 0, stream>>>(
        feat, Wq, bq, Wk, bk, Wv, bv, Qt, Kt, Vm);

    flash_kernel<<<dim3(BB * 32 * KS), 256, 0, stream>>>(
        Qt, Kt, Vm, Opart, Mp, Lp);

    combine_kernel<<<dim3(BB, NN / 32), 256, 0, stream>>>(
        Opart, Mp, Lp, feat, wgt, out);
}